// Round 2
// 787.771 us; speedup vs baseline: 1.0910x; 1.0910x over previous
//
#include <hip/hip_runtime.h>
#include <math.h>

// out[b,m,v,t,s] = softmax_s( sum_o (W1·X)[o,t] * (W2·X)[o,s] ),
// X[c,t] = x[b,c,t,v,m].  B=16, C=256, T=256, V=25, M=2, O=128.
//
// R4 = R3 resubmit (R3 bench died on container acquisition, no kernel signal).
// Stage1: split-f16 MFMA GEMM (v = hi + lo in f16; three products
//   Ah·Bh + Ah·Bl + Al·Bh on mfma_f32_16x16x32_f16, fp32 accum —
//   error ~2^-22 relative, fp32-equivalent for the 0.0039 absmax budget).
//   W1/W2 pre-split once into f16 hi/lo planes in the ws tail (prep_w).
//   A-fragments (W) load 16B/lane straight from L2 (no LDS; each 64B line
//   fully consumed by a 4-lane group). X converted in-kernel, staged via a
//   10 KB LDS tile [t][k] (stride 40 f16 = 80 B: 16B-aligned b128 rows,
//   bank pattern 20*t%32 = 2-way = free), next-chunk x prefetched over MFMA.
// Stage 2 (unchanged): per (b,vm): scores = s1^T s2 (256x256, K=128) + fused
//   row softmax. Multi-pass over b sized by ws_size.

#define C_DIM 256
#define T_DIM 256
#define V_DIM 25
#define M_DIM 2
#define O_DIM 128
#define O2    (O_DIM * 2)             /* 256 */
#define N_DIM (T_DIM * V_DIM * M_DIM) /* 12800 */
#define VM    (V_DIM * M_DIM)         /* 50 */

typedef _Float16 half8 __attribute__((ext_vector_type(8)));
typedef float f32x4 __attribute__((ext_vector_type(4)));

// ---------------- prep: split W1,W2 (fp32) into f16 hi/lo [o2=256][c=256] ---
__global__ __launch_bounds__(256)
void prep_w(const float* __restrict__ W1, const float* __restrict__ W2,
            _Float16* __restrict__ Wh, _Float16* __restrict__ Wl) {
    const int o2 = blockIdx.x;
    const int c  = threadIdx.x;
    const float w = (o2 < O_DIM) ? W1[(size_t)o2 * C_DIM + c]
                                 : W2[(size_t)(o2 - O_DIM) * C_DIM + c];
    const _Float16 h = (_Float16)w;
    Wh[(size_t)o2 * C_DIM + c] = h;
    Wl[(size_t)o2 * C_DIM + c] = (_Float16)(w - (float)h);
}

// ---------------- Stage 1: 256(o2) x 64(t) per block, split-f16 MFMA --------
// 4 waves; wave w owns o2 in [64w, 64w+64). Per K-chunk (32 c):
//   A-frag: lane l reads Wh/Wl[o2row = base + i*16 + (l&15)][kc + 8*(l>>4)..+8]
//   B-frag: LDS Bh/Bl[t = j*16 + (l&15)][8*(l>>4)..+8]   (layout [t][k])
//   D: row(o2) = 4*(l>>4)+r, col(t) = l&15   [guide §3, m89-verified]
__global__ __launch_bounds__(256)
void stage1_gemm(const float* __restrict__ x,
                 const _Float16* __restrict__ Wh, const _Float16* __restrict__ Wl,
                 float* __restrict__ ws, int b0) {
    const int b  = b0 + blockIdx.z;
    const int vm = blockIdx.y;
    const int t0 = blockIdx.x * 64;
    const float* xb = x + (size_t)b * C_DIM * N_DIM;
    float* outv = ws + ((size_t)blockIdx.z * VM + vm) * ((size_t)O2 * T_DIM);

    __shared__ __attribute__((aligned(16))) _Float16 Bh[64][40];
    __shared__ __attribute__((aligned(16))) _Float16 Bl[64][40];

    const int tid  = threadIdx.x;
    const int lane = tid & 63;
    const int wv   = tid >> 6;       // wave 0..3 -> o2 base = wv*64
    const int l15  = lane & 15;
    const int lg   = lane >> 4;      // 0..3

    // X staging: thread owns (t = tid&63, k sub-row block (tid>>6)*8)
    const int xt  = tid & 63;
    const int xkb = (tid >> 6) * 8;
    const float* xcol = xb + (size_t)(t0 + xt) * VM + vm;  // + c*N_DIM

    // W fragment base: row = wv*64 + l15 (+ i*16), k-offset 8*lg (+ kc)
    const size_t wbase = (size_t)(wv * 64 + l15) * C_DIM + 8 * lg;

    f32x4 acc[4][4] = {};   // [i: o2 sub][j: t sub]

    float xv[8];
    #pragma unroll
    for (int j = 0; j < 8; j++)
        xv[j] = xcol[(size_t)(xkb + j) * N_DIM];

    for (int kc = 0; kc < C_DIM; kc += 32) {
        // convert this chunk's x to hi/lo f16
        half8 hv, lv;
        #pragma unroll
        for (int j = 0; j < 8; j++) {
            const _Float16 h = (_Float16)xv[j];
            hv[j] = h;
            lv[j] = (_Float16)(xv[j] - (float)h);
        }
        __syncthreads();                       // prev chunk's readers done
        *(half8*)&Bh[xt][xkb] = hv;            // 16B-aligned ds_write_b128
        *(half8*)&Bl[xt][xkb] = lv;

        // prefetch next chunk's x (HBM latency hides under MFMA below)
        if (kc + 32 < C_DIM) {
            #pragma unroll
            for (int j = 0; j < 8; j++)
                xv[j] = xcol[(size_t)(kc + 32 + xkb + j) * N_DIM];
        }

        // A fragments straight from L2 (Wh/Wl are 128 KB planes, fully hot)
        half8 ah[4], al[4];
        #pragma unroll
        for (int i = 0; i < 4; i++) {
            const size_t wrow = wbase + (size_t)i * 16 * C_DIM + kc;
            ah[i] = *(const half8*)(Wh + wrow);
            al[i] = *(const half8*)(Wl + wrow);
        }
        __syncthreads();                       // B tile visible

        half8 bh[4], bl[4];
        #pragma unroll
        for (int j = 0; j < 4; j++) {
            bh[j] = *(const half8*)&Bh[j * 16 + l15][8 * lg];
            bl[j] = *(const half8*)&Bl[j * 16 + l15][8 * lg];
        }

        #pragma unroll
        for (int i = 0; i < 4; i++)
            #pragma unroll
            for (int j = 0; j < 4; j++) {
                acc[i][j] = __builtin_amdgcn_mfma_f32_16x16x32_f16(ah[i], bh[j], acc[i][j], 0, 0, 0);
                acc[i][j] = __builtin_amdgcn_mfma_f32_16x16x32_f16(ah[i], bl[j], acc[i][j], 0, 0, 0);
                acc[i][j] = __builtin_amdgcn_mfma_f32_16x16x32_f16(al[i], bh[j], acc[i][j], 0, 0, 0);
            }
    }

    // store: D row = 4*lg + r (o2), col = l15 (t); 16 lanes cover 64B runs
    #pragma unroll
    for (int i = 0; i < 4; i++) {
        #pragma unroll
        for (int j = 0; j < 4; j++) {
            float* p = outv + (size_t)(wv * 64 + i * 16 + lg * 4) * T_DIM + t0 + j * 16 + l15;
            #pragma unroll
            for (int r = 0; r < 4; r++)
                p[(size_t)r * T_DIM] = acc[i][j][r];
        }
    }
}

// ------------- Stage 2: scores = s1^T s2 (64x256 tile) + fused softmax -------
__global__ __launch_bounds__(512)
void stage2_softmax(const float* __restrict__ ws, float* __restrict__ out, int b0) {
    const int bl = blockIdx.z;
    const int b  = b0 + bl;
    const int vm = blockIdx.y;            // = v*2 + m
    const int t0 = blockIdx.x * 64;
    const float* s12b = ws + ((size_t)bl * VM + vm) * ((size_t)O2 * T_DIM);
    const float* s1 = s12b;                          // [128][256] : o x t
    const float* s2 = s12b + (size_t)O_DIM * T_DIM;  // [128][256] : o x s

    __shared__ float At[32][68];    // [k][t]  (64 + 4 pad)
    __shared__ float Bt[32][260];   // [k][s]  (256 + 4 pad)

    const int tid = threadIdx.x;
    const int ty = tid >> 5;        // 0..15 : t micro-rows
    const int tx = tid & 31;        // 0..31 : s micro-cols

    const int lr = tid >> 4;        // 0..31  load row (o within chunk)
    const int lt = (tid & 15) * 4;  // A col
    const int ls = (tid & 15) * 16; // B col base

    float acc[4][8] = {};

    for (int kc = 0; kc < O_DIM; kc += 32) {
        float4 av  = *(const float4*)&s1[(size_t)(kc + lr) * T_DIM + t0 + lt];
        float4 bv0 = *(const float4*)&s2[(size_t)(kc + lr) * T_DIM + ls];
        float4 bv1 = *(const float4*)&s2[(size_t)(kc + lr) * T_DIM + ls + 4];
        float4 bv2 = *(const float4*)&s2[(size_t)(kc + lr) * T_DIM + ls + 8];
        float4 bv3 = *(const float4*)&s2[(size_t)(kc + lr) * T_DIM + ls + 12];
        __syncthreads();
        *(float4*)&At[lr][lt]      = av;
        *(float4*)&Bt[lr][ls]      = bv0;
        *(float4*)&Bt[lr][ls + 4]  = bv1;
        *(float4*)&Bt[lr][ls + 8]  = bv2;
        *(float4*)&Bt[lr][ls + 12] = bv3;
        __syncthreads();

        #pragma unroll 2
        for (int k = 0; k < 32; k++) {
            float4 a  = *(const float4*)&At[k][ty * 4];
            float4 b0 = *(const float4*)&Bt[k][tx * 8];
            float4 b1 = *(const float4*)&Bt[k][tx * 8 + 4];
            float av_[4] = {a.x, a.y, a.z, a.w};
            float bv_[8] = {b0.x, b0.y, b0.z, b0.w, b1.x, b1.y, b1.z, b1.w};
            #pragma unroll
            for (int i = 0; i < 4; i++)
                #pragma unroll
                for (int j = 0; j < 8; j++)
                    acc[i][j] = fmaf(av_[i], bv_[j], acc[i][j]);
        }
    }

    // fused softmax over s (row = fixed t); row spread over 32 lanes x 8 vals
    const int mm = vm & 1;
    const int vv = vm >> 1;
    const size_t rowbase0 = (((size_t)b * M_DIM + mm) * V_DIM + vv) * T_DIM;

    #pragma unroll
    for (int i = 0; i < 4; i++) {
        float mx = -INFINITY;
        #pragma unroll
        for (int j = 0; j < 8; j++) mx = fmaxf(mx, acc[i][j]);
        #pragma unroll
        for (int d = 16; d >= 1; d >>= 1) mx = fmaxf(mx, __shfl_xor(mx, d));
        float p[8];
        float l = 0.f;
        #pragma unroll
        for (int j = 0; j < 8; j++) { p[j] = __expf(acc[i][j] - mx); l += p[j]; }
        #pragma unroll
        for (int d = 16; d >= 1; d >>= 1) l += __shfl_xor(l, d);
        const float inv = 1.0f / l;
        float4 r0 = {p[0] * inv, p[1] * inv, p[2] * inv, p[3] * inv};
        float4 r1 = {p[4] * inv, p[5] * inv, p[6] * inv, p[7] * inv};
        float* orow = out + (rowbase0 + t0 + ty * 4 + i) * T_DIM + tx * 8;
        *(float4*)orow       = r0;
        *((float4*)orow + 1) = r1;
    }
}

extern "C" void kernel_launch(void* const* d_in, const int* in_sizes, int n_in,
                              void* d_out, int out_size, void* d_ws, size_t ws_size,
                              hipStream_t stream) {
    const float* x  = (const float*)d_in[0];
    const float* W1 = (const float*)d_in[1];
    const float* W2 = (const float*)d_in[2];
    float* out = (float*)d_out;
    float* ws  = (float*)d_ws;

    const size_t per_b_bytes = (size_t)VM * O2 * T_DIM * sizeof(float); // 13.1 MB
    const size_t wtail = 2 * (size_t)O2 * C_DIM * sizeof(_Float16);     // 256 KB
    if (ws_size < wtail + per_b_bytes) return;
    const size_t wsplit_off = (ws_size - wtail) & ~(size_t)255;          // 256B-aligned
    _Float16* Whp = (_Float16*)((char*)ws + wsplit_off);
    _Float16* Wlp = Whp + (size_t)O2 * C_DIM;

    int nb = (int)(wsplit_off / per_b_bytes);
    if (nb < 1) return;
    if (nb > 16) nb = 16;

    prep_w<<<dim3(O2), C_DIM, 0, stream>>>(W1, W2, Whp, Wlp);

    for (int b0 = 0; b0 < 16; b0 += nb) {
        const int n = (16 - b0 < nb) ? (16 - b0) : nb;
        stage1_gemm<<<dim3(T_DIM / 64, VM, n), 256, 0, stream>>>(x, Whp, Wlp, ws, b0);
        stage2_softmax<<<dim3(T_DIM / 64, VM, n), 512, 0, stream>>>(ws, out, b0);
    }
}

// Round 3
// 767.337 us; speedup vs baseline: 1.1201x; 1.0266x over previous
//
#include <hip/hip_runtime.h>
#include <math.h>

// out[b,m,v,t,s] = softmax_s( sum_o (W1·X)[o,t] * (W2·X)[o,s] ),
// X[c,t] = x[b,c,t,v,m].  B=16, C=256, T=256, V=25, M=2, O=128.
//
// R5: kill all strided memory ops (R4 post-mortem: stage1 was bound by
//   64-lines-per-instr strided x loads, ~340 us of line transactions).
//   n = t*50+vm is CONTIGUOUS in x — so:
//   Stage1: block = 64 contiguous n x 256 o2. Coalesced float4 x loads ->
//     LDS [k][n] packed (f16 hi | f16 lo) u32, stride 65 (2-way banks = free).
//     Split-f16 MFMA (Ah*Bh + Ah*Bl + Al*Bh), W hi/lo planes from L2.
//     Stores s12 as f16 hi/lo planes ws[n][o2] (o-contiguous half4 writes) —
//     this store layout IS the vm-transpose.
//   Stage2: MFMA GEMM (was VALU): for (b,vm), A rows = ws[t*50+vm][0..128),
//     B rows = ws[s*50+vm][128..256) — o innermost = fragment-native 16B/lane
//     loads from L2, no LDS. Same 3-product split, fused row softmax.

#define C_DIM 256
#define T_DIM 256
#define V_DIM 25
#define M_DIM 2
#define O_DIM 128
#define O2    256
#define N_DIM (T_DIM * V_DIM * M_DIM) /* 12800 */
#define VM    (V_DIM * M_DIM)         /* 50 */

typedef _Float16 half8 __attribute__((ext_vector_type(8)));
typedef _Float16 half4 __attribute__((ext_vector_type(4)));
typedef float f32x4 __attribute__((ext_vector_type(4)));

static __device__ __forceinline__ unsigned pack_hl(float v) {
    const _Float16 h = (_Float16)v;
    const _Float16 l = (_Float16)(v - (float)h);
    return (unsigned)__builtin_bit_cast(unsigned short, h) |
           ((unsigned)__builtin_bit_cast(unsigned short, l) << 16);
}

// ---------------- prep: split W1,W2 (fp32) into f16 hi/lo [o2=256][c=256] ---
__global__ __launch_bounds__(256)
void prep_w(const float* __restrict__ W1, const float* __restrict__ W2,
            _Float16* __restrict__ Wh, _Float16* __restrict__ Wl) {
    const int o2 = blockIdx.x;
    const int c  = threadIdx.x;
    const float w = (o2 < O_DIM) ? W1[(size_t)o2 * C_DIM + c]
                                 : W2[(size_t)(o2 - O_DIM) * C_DIM + c];
    const _Float16 h = (_Float16)w;
    Wh[(size_t)o2 * C_DIM + c] = h;
    Wl[(size_t)o2 * C_DIM + c] = (_Float16)(w - (float)h);
}

// ---------------- Stage 1: 256(o2) x 64(n) per block, all-coalesced ---------
// 4 waves; wave wv owns o2 in [64wv, 64wv+64).
//   A-frag: lane l reads Wh/Wl[o2 = 64wv + i*16 + (l&15)][kc + 8*(l>>4)..+8]
//   B-frag: LDS (hi|lo) u32 Bhl[k = 8*(l>>4)+ii][n = j*16 + (l&15)]
//   D: o2 = 64wv + 16i + 4*(l>>4) + r, n = n0 + 16j + (l&15)  [R3 HW-verified]
__global__ __launch_bounds__(256)
void stage1_gemm(const float* __restrict__ x,
                 const _Float16* __restrict__ Wh, const _Float16* __restrict__ Wl,
                 _Float16* __restrict__ ws, int b0) {
    const int b  = b0 + blockIdx.y;
    const int n0 = blockIdx.x * 64;
    const float* xb = x + (size_t)b * C_DIM * N_DIM;
    _Float16* outh = ws + (size_t)blockIdx.y * (2 * (size_t)N_DIM * O2);
    _Float16* outl = outh + (size_t)N_DIM * O2;

    __shared__ unsigned Bhl[32][65];   // [k][n] (hi|lo) packed; 65: 2-way banks

    const int tid  = threadIdx.x;
    const int lane = tid & 63;
    const int wv   = tid >> 6;
    const int l15  = lane & 15;
    const int lg   = lane >> 4;

    const int lr = tid >> 4;           // 0..15 : k rows lr, lr+16
    const int lc = (tid & 15) * 4;     // n cols lc..lc+3

    const size_t wbase = (size_t)(wv * 64 + l15) * C_DIM + 8 * lg;

    f32x4 acc[4][4] = {};

    float4 xa = *(const float4*)&xb[(size_t)lr * N_DIM + n0 + lc];
    float4 xc = *(const float4*)&xb[(size_t)(lr + 16) * N_DIM + n0 + lc];

    for (int kc = 0; kc < C_DIM; kc += 32) {
        unsigned pa0 = pack_hl(xa.x), pa1 = pack_hl(xa.y),
                 pa2 = pack_hl(xa.z), pa3 = pack_hl(xa.w);
        unsigned pc0 = pack_hl(xc.x), pc1 = pack_hl(xc.y),
                 pc2 = pack_hl(xc.z), pc3 = pack_hl(xc.w);
        __syncthreads();                      // prev chunk's readers done
        Bhl[lr][lc + 0] = pa0;  Bhl[lr][lc + 1] = pa1;
        Bhl[lr][lc + 2] = pa2;  Bhl[lr][lc + 3] = pa3;
        Bhl[lr + 16][lc + 0] = pc0;  Bhl[lr + 16][lc + 1] = pc1;
        Bhl[lr + 16][lc + 2] = pc2;  Bhl[lr + 16][lc + 3] = pc3;

        if (kc + 32 < C_DIM) {                // prefetch next chunk (coalesced)
            xa = *(const float4*)&xb[(size_t)(kc + 32 + lr) * N_DIM + n0 + lc];
            xc = *(const float4*)&xb[(size_t)(kc + 32 + lr + 16) * N_DIM + n0 + lc];
        }

        half8 ah[4], al[4];                   // W frags from L2 (256 KB hot)
        #pragma unroll
        for (int i = 0; i < 4; i++) {
            const size_t wrow = wbase + (size_t)(i * 16) * C_DIM + kc;
            ah[i] = *(const half8*)(Wh + wrow);
            al[i] = *(const half8*)(Wl + wrow);
        }
        __syncthreads();                      // B tile visible

        #pragma unroll
        for (int j = 0; j < 4; j++) {
            half8 bh, bl;
            #pragma unroll
            for (int ii = 0; ii < 8; ii++) {
                const unsigned u = Bhl[8 * lg + ii][j * 16 + l15];
                bh[ii] = __builtin_bit_cast(_Float16, (unsigned short)(u & 0xffffu));
                bl[ii] = __builtin_bit_cast(_Float16, (unsigned short)(u >> 16));
            }
            #pragma unroll
            for (int i = 0; i < 4; i++) {
                acc[i][j] = __builtin_amdgcn_mfma_f32_16x16x32_f16(ah[i], bh, acc[i][j], 0, 0, 0);
                acc[i][j] = __builtin_amdgcn_mfma_f32_16x16x32_f16(ah[i], bl, acc[i][j], 0, 0, 0);
                acc[i][j] = __builtin_amdgcn_mfma_f32_16x16x32_f16(al[i], bh, acc[i][j], 0, 0, 0);
            }
        }
    }

    // store hi/lo f16 planes ws[n][o2]: half4 per (i,j), o-contiguous
    #pragma unroll
    for (int i = 0; i < 4; i++) {
        #pragma unroll
        for (int j = 0; j < 4; j++) {
            const int n  = n0 + j * 16 + l15;
            const int oc = wv * 64 + i * 16 + lg * 4;
            half4 hh, ll;
            #pragma unroll
            for (int r = 0; r < 4; r++) {
                const float v = acc[i][j][r];
                const _Float16 h = (_Float16)v;
                hh[r] = h;
                ll[r] = (_Float16)(v - (float)h);
            }
            *(half4*)&outh[(size_t)n * O2 + oc] = hh;
            *(half4*)&outl[(size_t)n * O2 + oc] = ll;
        }
    }
}

// ------------- Stage 2: scores = s1^T s2 via MFMA + fused softmax -----------
// block 256 thr (4 waves), grid (4 t-tiles, 50 vm, nb). Wave wv: t rows
// [t0+16wv, +16). A row t -> ws[t*50+vm][kc+8lg..+8] (o2<128); B row s ->
// ws[s*50+vm][128+kc+8lg..+8]. D: t = t0+16wv+4lg+r, s = 16st+l15.
__global__ __launch_bounds__(256)
void stage2_softmax(const _Float16* __restrict__ ws, float* __restrict__ out, int b0) {
    const int b  = b0 + blockIdx.z;
    const int vm = blockIdx.y;
    const int t0 = blockIdx.x * 64;
    const _Float16* ph = ws + (size_t)blockIdx.z * (2 * (size_t)N_DIM * O2);
    const _Float16* pl = ph + (size_t)N_DIM * O2;

    const int tid  = threadIdx.x;
    const int lane = tid & 63;
    const int wv   = tid >> 6;
    const int l15  = lane & 15;
    const int lg   = lane >> 4;

    const size_t aoff  = ((size_t)(t0 + wv * 16 + l15) * VM + vm) * O2 + 8 * lg;
    const size_t boff  = ((size_t)l15 * VM + vm) * O2 + O_DIM + 8 * lg;
    const size_t bstep = (size_t)16 * VM * O2;   // +16 s rows

    f32x4 acc[16] = {};

    for (int kc = 0; kc < O_DIM; kc += 32) {
        const half8 ah = *(const half8*)(ph + aoff + kc);
        const half8 al = *(const half8*)(pl + aoff + kc);
        #pragma unroll
        for (int st = 0; st < 16; st++) {
            const half8 bh = *(const half8*)(ph + boff + (size_t)st * bstep + kc);
            const half8 bl = *(const half8*)(pl + boff + (size_t)st * bstep + kc);
            acc[st] = __builtin_amdgcn_mfma_f32_16x16x32_f16(ah, bh, acc[st], 0, 0, 0);
            acc[st] = __builtin_amdgcn_mfma_f32_16x16x32_f16(ah, bl, acc[st], 0, 0, 0);
            acc[st] = __builtin_amdgcn_mfma_f32_16x16x32_f16(al, bh, acc[st], 0, 0, 0);
        }
    }

    const int mm = vm & 1;
    const int vv = vm >> 1;

    #pragma unroll
    for (int r = 0; r < 4; r++) {
        float mx = -INFINITY;
        #pragma unroll
        for (int st = 0; st < 16; st++) mx = fmaxf(mx, acc[st][r]);
        #pragma unroll
        for (int d = 8; d >= 1; d >>= 1) mx = fmaxf(mx, __shfl_xor(mx, d));
        float p[16];
        float sum = 0.f;
        #pragma unroll
        for (int st = 0; st < 16; st++) { p[st] = __expf(acc[st][r] - mx); sum += p[st]; }
        #pragma unroll
        for (int d = 8; d >= 1; d >>= 1) sum += __shfl_xor(sum, d);
        const float inv = 1.0f / sum;
        const int t = t0 + wv * 16 + lg * 4 + r;
        float* orow = out + ((((size_t)b * M_DIM + mm) * V_DIM + vv) * T_DIM + t) * T_DIM;
        #pragma unroll
        for (int st = 0; st < 16; st++)
            orow[st * 16 + l15] = p[st] * inv;
    }
}

extern "C" void kernel_launch(void* const* d_in, const int* in_sizes, int n_in,
                              void* d_out, int out_size, void* d_ws, size_t ws_size,
                              hipStream_t stream) {
    const float* x  = (const float*)d_in[0];
    const float* W1 = (const float*)d_in[1];
    const float* W2 = (const float*)d_in[2];
    float* out = (float*)d_out;
    _Float16* ws = (_Float16*)d_ws;

    const size_t per_b_bytes = 2 * (size_t)N_DIM * O2 * sizeof(_Float16); // 13.1 MB
    const size_t wtail = 2 * (size_t)O2 * C_DIM * sizeof(_Float16);       // 256 KB
    if (ws_size < wtail + per_b_bytes) return;
    const size_t wsplit_off = (ws_size - wtail) & ~(size_t)255;           // 256B-aligned
    _Float16* Whp = (_Float16*)((char*)d_ws + wsplit_off);
    _Float16* Wlp = Whp + (size_t)O2 * C_DIM;

    int nb = (int)(wsplit_off / per_b_bytes);
    if (nb < 1) return;
    if (nb > 16) nb = 16;

    prep_w<<<dim3(O2), C_DIM, 0, stream>>>(W1, W2, Whp, Wlp);

    for (int b0 = 0; b0 < 16; b0 += nb) {
        const int n = (16 - b0 < nb) ? (16 - b0) : nb;
        stage1_gemm<<<dim3(N_DIM / 64, n), 256, 0, stream>>>(x, Whp, Wlp, ws, b0);
        stage2_softmax<<<dim3(T_DIM / 64, VM, n), 256, 0, stream>>>(ws, out, b0);
    }
}